// Round 3
// baseline (799.223 us; speedup 1.0000x reference)
//
#include <hip/hip_runtime.h>

#define NN   100000
#define DIN  1152

// ---- ws layout (fp32): ------------------------------------------------
//  [0     .. 6144)  W0[u][v]  = w1_0[u,v] * inv_in                  (128x48)
//  [6144  .. 8192)  W1[u][v]  = w1_1[u,v] * w2_1[v] * inv_in*inv_h  (128x16)
//  [8192  ..10240)  W2[u][v]  = w1_2[u,v] * w2_2[v] * inv_in*inv_h  (128x16)
//  [10240 ..10256)  W20[v]    = w2_0[v] * inv_h                     (16)
// -----------------------------------------------------------------------

__global__ void __launch_bounds__(256) prep_weights(
    const float* __restrict__ w10, const float* __restrict__ w11,
    const float* __restrict__ w12, const float* __restrict__ w20,
    const float* __restrict__ w21, const float* __restrict__ w22,
    float* __restrict__ ws) {
  int t = blockIdx.x * 256 + threadIdx.x;
  const float inv_in = 0.08838834764831845f;          // 1/sqrt(128)
  const float inv_ih = 0.25f * 0.08838834764831845f;  // 1/sqrt(128)/sqrt(16)
  if (t < 6144) ws[t] = w10[t] * inv_in;
  if (t < 2048) {
    int v = t & 15;
    ws[6144 + t] = w11[t] * w21[v] * inv_ih;
    ws[8192 + t] = w12[t] * w22[v] * inv_ih;
  }
  if (t < 16) ws[10240 + t] = w20[t] * 0.25f;         // 1/sqrt(16)
}

__device__ __forceinline__ float silu(float t) {
  return t / (1.f + __expf(-t));
}

// Block = 256 threads = 4 waves covering the SAME 64 nodes.
// Wave w owns u-quarter [32w, 32w+32) of every matmul -> weight addresses stay
// wave-uniform (s_load), element index math stays compile-time after unroll.
__global__ void __launch_bounds__(256, 4) fused_node_kernel(
    const float* __restrict__ x, const float* __restrict__ ws,
    float* __restrict__ out) {
  // 25088 B, time-multiplexed:
  //  red0 = smem        [64][49]  phase-0 partial (wave2) ; later gbuf [64][33]
  //  red1 = smem + 3136 [64][49]  phase-0 partial (wave3/1); later obuf [3][64][9]
  __shared__ float smem[6272];
  float* red0 = smem;
  float* red1 = smem + 3136;
  float* gbuf = smem;          // alias red0 (safe: see sync sequence)
  float* obuf = smem + 3136;   // alias red1

  const int lane = threadIdx.x & 63;
  const int w    = threadIdx.x >> 6;          // 0..3
  const int nb   = blockIdx.x * 64;
  const int node = nb + lane;
  const int nrow = node < NN ? node : NN - 1; // clamp OOB lanes (no store later)
  const float4* __restrict__ xr =
      reinterpret_cast<const float4*>(x + (size_t)nrow * DIN);

  const float* __restrict__ W0  = ws;
  const float* __restrict__ W1  = ws + 6144;
  const float* __restrict__ W2  = ws + 8192;
  const float* __restrict__ W20 = ws + 10240;

  // ---------------- phase 0: partial y0 over u in [32w, 32w+32) ----------------
  float y0p[48];
  #pragma unroll
  for (int v = 0; v < 48; ++v) y0p[v] = 0.f;
  {
    const float* Wb = W0 + (32 * w) * 48;     // wave-uniform
    #pragma unroll
    for (int q = 0; q < 8; ++q) {
      float4 d = xr[8 * w + q];
      const float* wp = Wb + q * 192;
      #pragma unroll
      for (int v = 0; v < 48; ++v)
        y0p[v] = fmaf(d.x, wp[v],
                 fmaf(d.y, wp[48 + v],
                 fmaf(d.z, wp[96 + v],
                 fmaf(d.w, wp[144 + v], y0p[v]))));
    }
  }

  // ---------------- tree-reduce y0 into wave 0 ----------------
  if (w >= 2) {
    float* dst = (w == 2 ? red0 : red1) + lane * 49;
    #pragma unroll
    for (int v = 0; v < 48; ++v) dst[v] = y0p[v];
  }
  __syncthreads();                                        // S1
  if (w == 0) {
    const float* b = red0 + lane * 49;
    #pragma unroll
    for (int v = 0; v < 48; ++v) y0p[v] += b[v];
  } else if (w == 1) {
    float* b = red1 + lane * 49;
    #pragma unroll
    for (int v = 0; v < 48; ++v) { y0p[v] += b[v]; b[v] = y0p[v]; }
  }
  __syncthreads();                                        // S2

  // ---------------- wave 0: finish y0, SiLU, o0, publish g ----------------
  float g1[16], g2[16];
  float o0 = 0.f;
  if (w == 0) {
    const float* b = red1 + lane * 49;
    #pragma unroll
    for (int v = 0; v < 48; ++v) y0p[v] += b[v];
    #pragma unroll
    for (int v = 0; v < 16; ++v) o0 = fmaf(silu(y0p[v]), W20[v], o0);
    #pragma unroll
    for (int v = 0; v < 16; ++v) g1[v] = silu(y0p[16 + v]);
    #pragma unroll
    for (int v = 0; v < 16; ++v) g2[v] = silu(y0p[32 + v]);
    float* gp = gbuf + lane * 33;
    #pragma unroll
    for (int v = 0; v < 16; ++v) { gp[v] = g1[v]; gp[16 + v] = g2[v]; }
  }
  __syncthreads();                                        // S3
  if (w != 0) {
    const float* gp = gbuf + lane * 33;
    #pragma unroll
    for (int v = 0; v < 16; ++v) { g1[v] = gp[v]; g2[v] = gp[16 + v]; }
  }

  // ---------------- l=1: wave w handles u in [32w,32w+32) ----------------
  // elements r = 3u+i in [96w, 96w+96)  -> float4 idx 32+24w .. +24
  float o1p[3] = {0.f, 0.f, 0.f};
  {
    float t1[32];
    const float* Wb = W1 + (32 * w) * 16;     // wave-uniform
    #pragma unroll
    for (int uu = 0; uu < 32; ++uu) {
      float s = 0.f;
      #pragma unroll
      for (int v = 0; v < 16; ++v) s = fmaf(Wb[uu * 16 + v], g1[v], s);
      t1[uu] = s;
    }
    const float4* p = xr + 32 + 24 * w;
    #pragma unroll
    for (int k = 0; k < 24; ++k) {            // c = 4k+m: uu=c/3, i=c%3 (static)
      float4 d = p[k];
      o1p[(4 * k + 0) % 3] = fmaf(d.x, t1[(4 * k + 0) / 3], o1p[(4 * k + 0) % 3]);
      o1p[(4 * k + 1) % 3] = fmaf(d.y, t1[(4 * k + 1) / 3], o1p[(4 * k + 1) % 3]);
      o1p[(4 * k + 2) % 3] = fmaf(d.z, t1[(4 * k + 2) / 3], o1p[(4 * k + 2) % 3]);
      o1p[(4 * k + 3) % 3] = fmaf(d.w, t1[(4 * k + 3) / 3], o1p[(4 * k + 3) % 3]);
    }
  }

  // ---------------- l=2: wave w handles u in [32w,32w+32) ----------------
  // elements r = 5u+i in [160w, 160w+160) -> float4 idx 128+40w .. +40
  float o2p[5] = {0.f, 0.f, 0.f, 0.f, 0.f};
  {
    float t2[32];
    const float* Wb = W2 + (32 * w) * 16;     // wave-uniform
    #pragma unroll
    for (int uu = 0; uu < 32; ++uu) {
      float s = 0.f;
      #pragma unroll
      for (int v = 0; v < 16; ++v) s = fmaf(Wb[uu * 16 + v], g2[v], s);
      t2[uu] = s;
    }
    const float4* p = xr + 128 + 40 * w;
    #pragma unroll
    for (int k = 0; k < 40; ++k) {            // c = 4k+m: uu=c/5, i=c%5 (static)
      float4 d = p[k];
      o2p[(4 * k + 0) % 5] = fmaf(d.x, t2[(4 * k + 0) / 5], o2p[(4 * k + 0) % 5]);
      o2p[(4 * k + 1) % 5] = fmaf(d.y, t2[(4 * k + 1) / 5], o2p[(4 * k + 1) % 5]);
      o2p[(4 * k + 2) % 5] = fmaf(d.z, t2[(4 * k + 2) / 5], o2p[(4 * k + 2) % 5]);
      o2p[(4 * k + 3) % 5] = fmaf(d.w, t2[(4 * k + 3) / 5], o2p[(4 * k + 3) % 5]);
    }
  }

  // ---------------- reduce o across waves, wave 0 stores ----------------
  if (w != 0) {
    float* op = obuf + (w - 1) * 576 + lane * 9;
    #pragma unroll
    for (int i = 0; i < 3; ++i) op[i] = o1p[i];
    #pragma unroll
    for (int i = 0; i < 5; ++i) op[3 + i] = o2p[i];
  }
  __syncthreads();                                        // S4
  if (w == 0 && node < NN) {
    #pragma unroll
    for (int wi = 0; wi < 3; ++wi) {
      const float* op = obuf + wi * 576 + lane * 9;
      #pragma unroll
      for (int i = 0; i < 3; ++i) o1p[i] += op[i];
      #pragma unroll
      for (int i = 0; i < 5; ++i) o2p[i] += op[3 + i];
    }
    float* po = out + (size_t)node * 9;
    po[0] = o0;
    #pragma unroll
    for (int i = 0; i < 3; ++i) po[1 + i] = o1p[i];
    #pragma unroll
    for (int i = 0; i < 5; ++i) po[4 + i] = o2p[i];
  }
}

extern "C" void kernel_launch(void* const* d_in, const int* in_sizes, int n_in,
                              void* d_out, int out_size, void* d_ws, size_t ws_size,
                              hipStream_t stream) {
  const float* x   = (const float*)d_in[0];
  const float* w10 = (const float*)d_in[1];
  const float* w11 = (const float*)d_in[2];
  const float* w12 = (const float*)d_in[3];
  const float* w20 = (const float*)d_in[4];
  const float* w21 = (const float*)d_in[5];
  const float* w22 = (const float*)d_in[6];
  float* ws = (float*)d_ws;

  prep_weights<<<24, 256, 0, stream>>>(w10, w11, w12, w20, w21, w22, ws);

  int blocks = (NN + 63) / 64;   // 1563 blocks x 4 waves, 64 nodes/block
  fused_node_kernel<<<blocks, 256, 0, stream>>>(x, ws, (float*)d_out);
}